// Round 1
// baseline (17.627 us; speedup 1.0000x reference)
//
#include <hip/hip_runtime.h>

// Problem: out[b] = sum_{distinct v in x[:,b]} W[v] + b_lut[0] + bias[0]
//   x: (200, 1024) int, W: (1, 100000) f32, out: (1024,) f32
// One block per batch column. Dedup via first-occurrence scan in LDS.

#define VSIZE  100000
#define LENGTH 200
#define BATCH  1024

__global__ __launch_bounds__(256) void LR2_kernel(
    const int* __restrict__ x,
    const float* __restrict__ W,
    const float* __restrict__ b_lut,
    const float* __restrict__ bias,
    float* __restrict__ out)
{
    __shared__ int   toks[LENGTH];
    __shared__ float wsum[4];

    const int b = blockIdx.x;
    const int t = threadIdx.x;

    int tok = -1;
    if (t < LENGTH) {
        tok = x[t * BATCH + b];
        toks[t] = tok;
    }
    __syncthreads();

    float contrib = 0.0f;
    if (t < LENGTH) {
        bool first = true;
        // At iteration j, every lagging lane reads toks[j] -> LDS broadcast.
        for (int j = 0; j < t; ++j) {
            if (toks[j] == tok) { first = false; break; }
        }
        if (first) contrib = W[tok];
    }

    // Wave (64-lane) shuffle reduction.
    for (int off = 32; off > 0; off >>= 1)
        contrib += __shfl_down(contrib, off, 64);

    const int wave = t >> 6;
    const int lane = t & 63;
    if (lane == 0) wsum[wave] = contrib;
    __syncthreads();

    if (t == 0) {
        float s = wsum[0] + wsum[1] + wsum[2] + wsum[3];
        out[b] = s + b_lut[0] + bias[0];
    }
}

extern "C" void kernel_launch(void* const* d_in, const int* in_sizes, int n_in,
                              void* d_out, int out_size, void* d_ws, size_t ws_size,
                              hipStream_t stream) {
    const int*   x     = (const int*)d_in[0];
    const float* W     = (const float*)d_in[1];
    const float* b_lut = (const float*)d_in[2];
    const float* bias  = (const float*)d_in[3];
    float*       out   = (float*)d_out;

    LR2_kernel<<<BATCH, 256, 0, stream>>>(x, W, b_lut, bias, out);
}

// Round 2
// 9.738 us; speedup vs baseline: 1.8102x; 1.8102x over previous
//
#include <hip/hip_runtime.h>

// out[b] = sum_{distinct v in x[:,b]} W[v] + b_lut[0] + bias[0]
//   x: (200, 1024) int32, W: (100000,) f32, out: (1024,) f32
// One block per batch column. Dedup via LDS open-addressing hash (O(L)),
// replacing the O(L^2) first-occurrence scan of R0.

#define VSIZE     100000
#define LENGTH    200
#define BATCH     1024
#define HASH_SIZE 1024          // load factor 200/1024 ~ 0.2, ~1.2 probes avg
#define EMPTY     0xFFFFFFFFu   // tokens < 100000, never collides with sentinel

__global__ __launch_bounds__(256) void LR2_kernel(
    const int* __restrict__ x,
    const float* __restrict__ W,
    const float* __restrict__ b_lut,
    const float* __restrict__ bias,
    float* __restrict__ out)
{
    __shared__ unsigned ht[HASH_SIZE];
    __shared__ float    wsum[4];

    const int b = blockIdx.x;
    const int t = threadIdx.x;

    // Issue the (latency-bound, uncoalesced) x gather first so it overlaps
    // with the hash-table clear.
    unsigned tok = EMPTY;
    if (t < LENGTH) tok = (unsigned)x[t * BATCH + b];

    #pragma unroll
    for (int i = t; i < HASH_SIZE; i += 256) ht[i] = EMPTY;
    __syncthreads();

    float contrib = 0.0f;
    if (t < LENGTH) {
        unsigned h = (tok * 2654435761u) >> 22;  // Knuth hash, top 10 bits
        for (;;) {
            unsigned old = atomicCAS(&ht[h], EMPTY, tok);
            if (old == EMPTY) {          // we own the first occurrence
                contrib = W[tok];
                break;
            }
            if (old == tok) break;       // duplicate, contributes nothing
            h = (h + 1) & (HASH_SIZE - 1);
        }
    }

    // Wave (64-lane) shuffle reduction, then cross-wave via LDS.
    for (int off = 32; off > 0; off >>= 1)
        contrib += __shfl_down(contrib, off, 64);

    const int wave = t >> 6;
    const int lane = t & 63;
    if (lane == 0) wsum[wave] = contrib;
    __syncthreads();

    if (t == 0) {
        float s = wsum[0] + wsum[1] + wsum[2] + wsum[3];
        out[b] = s + b_lut[0] + bias[0];
    }
}

extern "C" void kernel_launch(void* const* d_in, const int* in_sizes, int n_in,
                              void* d_out, int out_size, void* d_ws, size_t ws_size,
                              hipStream_t stream) {
    const int*   x     = (const int*)d_in[0];
    const float* W     = (const float*)d_in[1];
    const float* b_lut = (const float*)d_in[2];
    const float* bias  = (const float*)d_in[3];
    float*       out   = (float*)d_out;

    LR2_kernel<<<BATCH, 256, 0, stream>>>(x, W, b_lut, bias, out);
}